// Round 4
// baseline (84.448 us; speedup 1.0000x reference)
//
#include <hip/hip_runtime.h>
#include <hip/hip_bf16.h>

#define B_N 4096
#define E_N 64
#define D_N 1024
#define ROWS 16

typedef __bf16 bf16x8 __attribute__((ext_vector_type(8)));
typedef __bf16 bf16x4 __attribute__((ext_vector_type(4)));
typedef float f32x4 __attribute__((ext_vector_type(4)));

// ws layout (bytes):
// [0, 4096)        sinv   (1024 f32)
// [4096, 4352)     Ak     (64 f32)
// [4352, 135424)   sk_bf16 [64][1024]   (sigma_inv * keys, K-major)
// [135424, 266496) kT_bf16 [1024][64]   (raw keys transposed, K(=e)-major)

__global__ __launch_bounds__(256) void prep_kernel(
    const float* __restrict__ keys, const float* __restrict__ lsig,
    float* __restrict__ sinv, float* __restrict__ ak,
    __bf16* __restrict__ sk, __bf16* __restrict__ kT)
{
  __shared__ float red[4];
  __shared__ __bf16 tl[64][72];          // transpose tile, +8 pad
  const int bid = blockIdx.x;
  const int t = threadIdx.x;

  if (bid < 64) {
    // ---- per-expert: sinv, sk = sinv*keys (bf16), Ak = sum sinv*k^2 ----
    const int e = bid;
    const float4 k4 = *(const float4*)(keys + e * D_N + 4 * t);
    const float4 l4 = *(const float4*)(lsig + 4 * t);
    float4 s4;
    s4.x = expf(-l4.x); s4.y = expf(-l4.y); s4.z = expf(-l4.z); s4.w = expf(-l4.w);
    if (e == 0) *(float4*)(sinv + 4 * t) = s4;
    const float4 sk4 = make_float4(s4.x * k4.x, s4.y * k4.y, s4.z * k4.z, s4.w * k4.w);
    bf16x4 skb;
    skb[0] = (__bf16)sk4.x; skb[1] = (__bf16)sk4.y; skb[2] = (__bf16)sk4.z; skb[3] = (__bf16)sk4.w;
    *(bf16x4*)(sk + e * D_N + 4 * t) = skb;
    float p = sk4.x * k4.x + sk4.y * k4.y + sk4.z * k4.z + sk4.w * k4.w;
    #pragma unroll
    for (int off = 32; off > 0; off >>= 1) p += __shfl_down(p, off);
    if ((t & 63) == 0) red[t >> 6] = p;
    __syncthreads();
    if (t == 0) ak[e] = red[0] + red[1] + red[2] + red[3];
  } else {
    // ---- transpose: kT[d][e] = (bf16) keys[e][d], 64-d slab per block ----
    const int d0 = (bid - 64) * 64;
    #pragma unroll
    for (int p = 0; p < 4; ++p) {
      const int e  = p * 16 + (t >> 4);
      const int dd = (t & 15) * 4;
      const float4 k4 = *(const float4*)(keys + (size_t)e * D_N + d0 + dd);
      tl[dd + 0][e] = (__bf16)k4.x; tl[dd + 1][e] = (__bf16)k4.y;
      tl[dd + 2][e] = (__bf16)k4.z; tl[dd + 3][e] = (__bf16)k4.w;
    }
    __syncthreads();
    #pragma unroll
    for (int p = 0; p < 2; ++p) {
      const int dd = p * 32 + (t >> 3);
      const int l8 = t & 7;
      const bf16x8 v = *(const bf16x8*)&tl[dd][l8 * 8];
      *(bf16x8*)(kT + (size_t)(d0 + dd) * E_N + l8 * 8) = v;
    }
  }
}

// 8-wave block, ROWS=16, grid=256. Critical-path-tightened schedule:
// stage -> bar -> GEMM1(splitK, both halves publish pacc) + kT prefetch
//       -> bar -> softmax(256 thr: combine+sim-store+softmax fused)
//       -> bar -> GEMM2 (first 4 d-tiles from prefetched regs)
__global__ __launch_bounds__(512, 2) void main_kernel(
    const float* __restrict__ z, const float* __restrict__ sinv,
    const float* __restrict__ ak, const __bf16* __restrict__ sk,
    const __bf16* __restrict__ kT,
    float* __restrict__ out_sim, float* __restrict__ out_we)
{
  constexpr int ZS = D_N + 8;            // bf16 elems; 16B-aligned rows
  __shared__ __bf16 zlds[ROWS * ZS];     // 33 KB
  __shared__ float azs[ROWS];
  __shared__ float pacc[2][4][16][20];   // [kh][et][row][ln], +4 pad (f4-aligned)
  __shared__ __bf16 wlds[ROWS][72];      // +8 pad

  const int t  = threadIdx.x;
  const int b0 = blockIdx.x * ROWS;

  const int wave = t >> 6;               // 0..7
  const int lane = t & 63;
  const int ln = lane & 15;
  const int q  = lane >> 4;
  const int et = wave & 3;               // expert tile 0..3
  const int kh = wave >> 2;              // K-half 0..1

  // softmax threads prefetch their ak quad early (L2, hidden under stage)
  f32x4 ak4 = {0.f, 0.f, 0.f, 0.f};
  if (t < 256) ak4 = *(const f32x4*)(ak + (t & 15) * 4);

  // ---------- stage z -> bf16 LDS; Az = sum s*z^2 (32 threads per row) ----------
  const int sr = t >> 5;                 // row 0..15
  const int sc = t & 31;
  const float* zrow = z + (size_t)(b0 + sr) * D_N;
  float az = 0.f;
  #pragma unroll
  for (int l = 0; l < 8; ++l) {
    const int c = sc * 4 + l * 128;
    const float4 z4 = *(const float4*)(zrow + c);
    const float4 s4 = *(const float4*)(sinv + c);
    az += s4.x * z4.x * z4.x + s4.y * z4.y * z4.y + s4.z * z4.z * z4.z + s4.w * z4.w * z4.w;
    bf16x4 zb;
    zb[0] = (__bf16)z4.x; zb[1] = (__bf16)z4.y; zb[2] = (__bf16)z4.z; zb[3] = (__bf16)z4.w;
    *(bf16x4*)(&zlds[sr * ZS + c]) = zb;
  }
  // reduce across the 32 lanes of this row (xor<=16 stays inside the group)
  az += __shfl_xor(az, 1);  az += __shfl_xor(az, 2);
  az += __shfl_xor(az, 4);  az += __shfl_xor(az, 8);
  az += __shfl_xor(az, 16);
  if (sc == 0) azs[sr] = az;

  // prefetch first 4 sk B-frags (global/L2, no LDS dependency)
  const __bf16* bp = sk + (size_t)(et * 16 + ln) * D_N + kh * 512 + q * 8;
  const bf16x8 bpf0 = *(const bf16x8*)(bp);
  const bf16x8 bpf1 = *(const bf16x8*)(bp + 32);
  const bf16x8 bpf2 = *(const bf16x8*)(bp + 64);
  const bf16x8 bpf3 = *(const bf16x8*)(bp + 96);

  __syncthreads();                       // zlds + azs ready

  // ---------- GEMM1 (split-K): each wave does 16 experts x 512 K ----------
  const __bf16* ap = &zlds[ln * ZS + kh * 512 + q * 8];
  f32x4 acc = {0.f, 0.f, 0.f, 0.f};
  {
    const bf16x8 a0 = *(const bf16x8*)(ap);
    acc = __builtin_amdgcn_mfma_f32_16x16x32_bf16(a0, bpf0, acc, 0, 0, 0);
    const bf16x8 a1 = *(const bf16x8*)(ap + 32);
    acc = __builtin_amdgcn_mfma_f32_16x16x32_bf16(a1, bpf1, acc, 0, 0, 0);
    const bf16x8 a2 = *(const bf16x8*)(ap + 64);
    acc = __builtin_amdgcn_mfma_f32_16x16x32_bf16(a2, bpf2, acc, 0, 0, 0);
    const bf16x8 a3 = *(const bf16x8*)(ap + 96);
    acc = __builtin_amdgcn_mfma_f32_16x16x32_bf16(a3, bpf3, acc, 0, 0, 0);
  }
  #pragma unroll
  for (int ks = 4; ks < 16; ++ks) {
    const bf16x8 bfr = *(const bf16x8*)(bp + ks * 32);
    const bf16x8 afr = *(const bf16x8*)(ap + ks * 32);
    acc = __builtin_amdgcn_mfma_f32_16x16x32_bf16(afr, bfr, acc, 0, 0, 0);
  }

  // publish partials (2-way bank alias only — free)
  #pragma unroll
  for (int i = 0; i < 4; ++i) pacc[kh][et][q * 4 + i][ln] = acc[i];

  // prefetch GEMM2's first 4 d-tiles of kT B-frags (global, no LDS dep)
  bf16x8 pb0a, pb0b, pb1a, pb1b, pb2a, pb2b, pb3a, pb3b;
  {
    const __bf16* kp;
    kp = kT + (size_t)((wave +  0) * 16 + ln) * E_N + q * 8;
    pb0a = *(const bf16x8*)(kp); pb0b = *(const bf16x8*)(kp + 32);
    kp = kT + (size_t)((wave +  8) * 16 + ln) * E_N + q * 8;
    pb1a = *(const bf16x8*)(kp); pb1b = *(const bf16x8*)(kp + 32);
    kp = kT + (size_t)((wave + 16) * 16 + ln) * E_N + q * 8;
    pb2a = *(const bf16x8*)(kp); pb2b = *(const bf16x8*)(kp + 32);
    kp = kT + (size_t)((wave + 24) * 16 + ln) * E_N + q * 8;
    pb3a = *(const bf16x8*)(kp); pb3b = *(const bf16x8*)(kp + 32);
  }

  __syncthreads();                       // pacc ready

  // ---------- fused combine + similarity store + softmax (256 threads) ----------
  // 16 rows x 16 threads; thread handles experts seg*4 .. seg*4+3
  if (t < 256) {
    const int row = t >> 4, seg = t & 15;
    const f32x4 p0 = *(const f32x4*)&pacc[0][seg >> 2][row][(seg & 3) * 4];
    const f32x4 p1 = *(const f32x4*)&pacc[1][seg >> 2][row][(seg & 3) * 4];
    const float azr = azs[row];
    f32x4 s;
    #pragma unroll
    for (int j = 0; j < 4; ++j) {
      const float dist = azr + ak4[j] - 2.0f * (p0[j] + p1[j]);
      s[j] = 1.0f / (1.0f + dist);
    }
    *(f32x4*)(out_sim + (size_t)(b0 + row) * E_N + seg * 4) = s;
    float mx = fmaxf(fmaxf(s[0], s[1]), fmaxf(s[2], s[3]));
    mx = fmaxf(mx, __shfl_xor(mx, 1));
    mx = fmaxf(mx, __shfl_xor(mx, 2));
    mx = fmaxf(mx, __shfl_xor(mx, 4));
    mx = fmaxf(mx, __shfl_xor(mx, 8));
    float v[4];
    float sum = 0.f;
    #pragma unroll
    for (int j = 0; j < 4; ++j) { v[j] = __expf(s[j] - mx); sum += v[j]; }
    sum += __shfl_xor(sum, 1);
    sum += __shfl_xor(sum, 2);
    sum += __shfl_xor(sum, 4);
    sum += __shfl_xor(sum, 8);
    const float inv = 1.0f / sum;
    bf16x4 wq;
    #pragma unroll
    for (int j = 0; j < 4; ++j) wq[j] = (__bf16)(v[j] * inv);
    *(bf16x4*)&wlds[row][seg * 4] = wq;
  }
  __syncthreads();                       // wlds ready

  // ---------- GEMM2: out[16 rows][1024] = w[16][64] @ keys[64][1024] ----------
  const bf16x8 a0 = *(const bf16x8*)&wlds[ln][q * 8];        // A: m=row, k=e
  const bf16x8 a1 = *(const bf16x8*)&wlds[ln][32 + q * 8];
  #pragma unroll
  for (int i = 0; i < 8; ++i) {
    const int dt = wave + 8 * i;
    const int d0 = dt * 16;
    bf16x8 b0f, b1f;
    if      (i == 0) { b0f = pb0a; b1f = pb0b; }
    else if (i == 1) { b0f = pb1a; b1f = pb1b; }
    else if (i == 2) { b0f = pb2a; b1f = pb2b; }
    else if (i == 3) { b0f = pb3a; b1f = pb3b; }
    else {
      const __bf16* kp = kT + (size_t)(d0 + ln) * E_N + q * 8;
      b0f = *(const bf16x8*)(kp);
      b1f = *(const bf16x8*)(kp + 32);
    }
    f32x4 o = {0.f, 0.f, 0.f, 0.f};
    o = __builtin_amdgcn_mfma_f32_16x16x32_bf16(a0, b0f, o, 0, 0, 0);
    o = __builtin_amdgcn_mfma_f32_16x16x32_bf16(a1, b1f, o, 0, 0, 0);
    #pragma unroll
    for (int j = 0; j < 4; ++j)
      out_we[(size_t)(b0 + q * 4 + j) * D_N + d0 + ln] = o[j];
  }
}

extern "C" void kernel_launch(void* const* d_in, const int* in_sizes, int n_in,
                              void* d_out, int out_size, void* d_ws, size_t ws_size,
                              hipStream_t stream)
{
  const float* z    = (const float*)d_in[0];
  const float* keys = (const float*)d_in[1];
  const float* ls   = (const float*)d_in[2];
  float* out_sim = (float*)d_out;
  float* out_we  = out_sim + (size_t)B_N * E_N;
  char* ws = (char*)d_ws;
  float*  sinv = (float*)(ws);
  float*  ak   = (float*)(ws + 4096);
  __bf16* sk   = (__bf16*)(ws + 4352);
  __bf16* kT   = (__bf16*)(ws + 135424);
  prep_kernel<<<80, 256, 0, stream>>>(keys, ls, sinv, ak, sk, kT);
  main_kernel<<<B_N / ROWS, 512, 0, stream>>>(z, sinv, ak, sk, kT, out_sim, out_we);
}

// Round 5
// 81.551 us; speedup vs baseline: 1.0355x; 1.0355x over previous
//
#include <hip/hip_runtime.h>
#include <hip/hip_bf16.h>

#define B_N 4096
#define E_N 64
#define D_N 1024
#define ROWS 16

typedef __bf16 bf16x8 __attribute__((ext_vector_type(8)));
typedef __bf16 bf16x4 __attribute__((ext_vector_type(4)));
typedef float f32x4 __attribute__((ext_vector_type(4)));

// ws layout (bytes):
// [0, 4096)        sinv   (1024 f32)
// [4096, 4352)     Ak     (64 f32)
// [4352, 135424)   sk_bf16 [64][1024]   (sigma_inv * keys, K-major)
// [135424, 266496) kT_bf16 [1024][64]   (raw keys transposed, K(=e)-major)

__global__ __launch_bounds__(256) void prep_kernel(
    const float* __restrict__ keys, const float* __restrict__ lsig,
    float* __restrict__ sinv, float* __restrict__ ak,
    __bf16* __restrict__ sk, __bf16* __restrict__ kT)
{
  __shared__ float red[4];
  __shared__ __bf16 tl[64][72];          // transpose tile, +8 pad
  const int bid = blockIdx.x;
  const int t = threadIdx.x;

  if (bid < 64) {
    // ---- per-expert: sinv, sk = sinv*keys (bf16), Ak = sum sinv*k^2 ----
    const int e = bid;
    const float4 k4 = *(const float4*)(keys + e * D_N + 4 * t);
    const float4 l4 = *(const float4*)(lsig + 4 * t);
    float4 s4;
    s4.x = expf(-l4.x); s4.y = expf(-l4.y); s4.z = expf(-l4.z); s4.w = expf(-l4.w);
    if (e == 0) *(float4*)(sinv + 4 * t) = s4;
    const float4 sk4 = make_float4(s4.x * k4.x, s4.y * k4.y, s4.z * k4.z, s4.w * k4.w);
    bf16x4 skb;
    skb[0] = (__bf16)sk4.x; skb[1] = (__bf16)sk4.y; skb[2] = (__bf16)sk4.z; skb[3] = (__bf16)sk4.w;
    *(bf16x4*)(sk + e * D_N + 4 * t) = skb;
    float p = sk4.x * k4.x + sk4.y * k4.y + sk4.z * k4.z + sk4.w * k4.w;
    #pragma unroll
    for (int off = 32; off > 0; off >>= 1) p += __shfl_down(p, off);
    if ((t & 63) == 0) red[t >> 6] = p;
    __syncthreads();
    if (t == 0) ak[e] = red[0] + red[1] + red[2] + red[3];
  } else {
    // ---- transpose: kT[d][e] = (bf16) keys[e][d], 64-d slab per block ----
    const int d0 = (bid - 64) * 64;
    #pragma unroll
    for (int p = 0; p < 4; ++p) {
      const int e  = p * 16 + (t >> 4);
      const int dd = (t & 15) * 4;
      const float4 k4 = *(const float4*)(keys + (size_t)e * D_N + d0 + dd);
      tl[dd + 0][e] = (__bf16)k4.x; tl[dd + 1][e] = (__bf16)k4.y;
      tl[dd + 2][e] = (__bf16)k4.z; tl[dd + 3][e] = (__bf16)k4.w;
    }
    __syncthreads();
    #pragma unroll
    for (int p = 0; p < 2; ++p) {
      const int dd = p * 32 + (t >> 3);
      const int l8 = t & 7;
      const bf16x8 v = *(const bf16x8*)&tl[dd][l8 * 8];
      *(bf16x8*)(kT + (size_t)(d0 + dd) * E_N + l8 * 8) = v;
    }
  }
}

// 16-wave (1024-thr) block, ROWS=16, grid=256: total chip traffic and MFMA
// count identical to the 81.1us R3 config, but 4 waves/SIMD (2x R3) so each
// barrier-locked phase has 2x the outstanding-load parallelism per CU.
// GEMM1 split-K quarters (4 et x 4 kq); GEMM2 4 d-tiles/wave; stage = one
// wave per z-row. No cross-phase register prefetch (64-VGPR ceiling).
__global__ __launch_bounds__(1024) void main_kernel(
    const float* __restrict__ z, const float* __restrict__ sinv,
    const float* __restrict__ ak, const __bf16* __restrict__ sk,
    const __bf16* __restrict__ kT,
    float* __restrict__ out_sim, float* __restrict__ out_we)
{
  constexpr int ZS = D_N + 8;            // bf16 elems; 16B-aligned rows
  __shared__ __bf16 zlds[ROWS * ZS];     // 33 KB
  __shared__ float azs[ROWS];
  __shared__ float pacc[4][4][16][20];   // [kq][et][row][ln], +4 pad; 20 KB
  __shared__ __bf16 wlds[ROWS][72];      // +8 pad

  const int t  = threadIdx.x;
  const int b0 = blockIdx.x * ROWS;

  const int wave = t >> 6;               // 0..15
  const int lane = t & 63;
  const int ln = lane & 15;
  const int q  = lane >> 4;
  const int et = wave & 3;               // expert tile 0..3
  const int kq = wave >> 2;              // K-quarter 0..3

  // softmax threads prefetch their ak quad early (tiny, 4 VGPRs)
  f32x4 ak4 = {0.f, 0.f, 0.f, 0.f};
  if (t < 256) ak4 = *(const f32x4*)(ak + (t & 15) * 4);

  // ---------- stage z -> bf16 LDS; Az = sum s*z^2 (one wave per row) ----------
  const int sr = wave;                   // row 0..15
  const int sc = lane;                   // 0..63
  const float* zrow = z + (size_t)(b0 + sr) * D_N;
  float az = 0.f;
  #pragma unroll
  for (int l = 0; l < 4; ++l) {
    const int c = sc * 4 + l * 256;
    const float4 z4 = *(const float4*)(zrow + c);
    const float4 s4 = *(const float4*)(sinv + c);
    az += s4.x * z4.x * z4.x + s4.y * z4.y * z4.y + s4.z * z4.z * z4.z + s4.w * z4.w * z4.w;
    bf16x4 zb;
    zb[0] = (__bf16)z4.x; zb[1] = (__bf16)z4.y; zb[2] = (__bf16)z4.z; zb[3] = (__bf16)z4.w;
    *(bf16x4*)(&zlds[sr * ZS + c]) = zb;
  }
  // full-wave butterfly reduce; lane 0 publishes
  az += __shfl_xor(az, 1);  az += __shfl_xor(az, 2);
  az += __shfl_xor(az, 4);  az += __shfl_xor(az, 8);
  az += __shfl_xor(az, 16); az += __shfl_xor(az, 32);
  if (sc == 0) azs[sr] = az;

  __syncthreads();                       // zlds + azs ready

  // ---------- GEMM1 (split-K quarters): 16 experts x 256 K per wave ----------
  const __bf16* bp = sk + (size_t)(et * 16 + ln) * D_N + kq * 256 + q * 8;
  const __bf16* ap = &zlds[ln * ZS + kq * 256 + q * 8];
  f32x4 acc = {0.f, 0.f, 0.f, 0.f};
  #pragma unroll
  for (int ks = 0; ks < 8; ++ks) {
    const bf16x8 bfr = *(const bf16x8*)(bp + ks * 32);
    const bf16x8 afr = *(const bf16x8*)(ap + ks * 32);
    acc = __builtin_amdgcn_mfma_f32_16x16x32_bf16(afr, bfr, acc, 0, 0, 0);
  }
  // publish partials (write pattern is 2-way bank alias only — free)
  #pragma unroll
  for (int i = 0; i < 4; ++i) pacc[kq][et][q * 4 + i][ln] = acc[i];

  __syncthreads();                       // pacc ready

  // ---------- fused combine + similarity store + softmax (256 threads) ----------
  // 16 rows x 16 threads; thread handles experts seg*4 .. seg*4+3
  if (t < 256) {
    const int row = t >> 4, seg = t & 15;
    const int pe = seg >> 2, pc = (seg & 3) * 4;
    f32x4 p = *(const f32x4*)&pacc[0][pe][row][pc];
    #pragma unroll
    for (int k = 1; k < 4; ++k) {
      const f32x4 pk = *(const f32x4*)&pacc[k][pe][row][pc];
      p[0] += pk[0]; p[1] += pk[1]; p[2] += pk[2]; p[3] += pk[3];
    }
    const float azr = azs[row];
    f32x4 s;
    #pragma unroll
    for (int j = 0; j < 4; ++j) {
      const float dist = azr + ak4[j] - 2.0f * p[j];
      s[j] = 1.0f / (1.0f + dist);
    }
    *(f32x4*)(out_sim + (size_t)(b0 + row) * E_N + seg * 4) = s;
    float mx = fmaxf(fmaxf(s[0], s[1]), fmaxf(s[2], s[3]));
    mx = fmaxf(mx, __shfl_xor(mx, 1));
    mx = fmaxf(mx, __shfl_xor(mx, 2));
    mx = fmaxf(mx, __shfl_xor(mx, 4));
    mx = fmaxf(mx, __shfl_xor(mx, 8));
    float v[4];
    float sum = 0.f;
    #pragma unroll
    for (int j = 0; j < 4; ++j) { v[j] = __expf(s[j] - mx); sum += v[j]; }
    sum += __shfl_xor(sum, 1);
    sum += __shfl_xor(sum, 2);
    sum += __shfl_xor(sum, 4);
    sum += __shfl_xor(sum, 8);
    const float inv = 1.0f / sum;
    bf16x4 wq;
    #pragma unroll
    for (int j = 0; j < 4; ++j) wq[j] = (__bf16)(v[j] * inv);
    *(bf16x4*)&wlds[row][seg * 4] = wq;
  }
  __syncthreads();                       // wlds ready

  // ---------- GEMM2: out[16 rows][1024] = w[16][64] @ keys[64][1024] ----------
  const bf16x8 a0 = *(const bf16x8*)&wlds[ln][q * 8];        // A: m=row, k=e
  const bf16x8 a1 = *(const bf16x8*)&wlds[ln][32 + q * 8];
  #pragma unroll
  for (int i = 0; i < 4; ++i) {
    const int dt = wave + 16 * i;
    const int d0 = dt * 16;
    const __bf16* kp = kT + (size_t)(d0 + ln) * E_N + q * 8;
    const bf16x8 b0f = *(const bf16x8*)(kp);
    const bf16x8 b1f = *(const bf16x8*)(kp + 32);
    f32x4 o = {0.f, 0.f, 0.f, 0.f};
    o = __builtin_amdgcn_mfma_f32_16x16x32_bf16(a0, b0f, o, 0, 0, 0);
    o = __builtin_amdgcn_mfma_f32_16x16x32_bf16(a1, b1f, o, 0, 0, 0);
    #pragma unroll
    for (int j = 0; j < 4; ++j)
      out_we[(size_t)(b0 + q * 4 + j) * D_N + d0 + ln] = o[j];
  }
}

extern "C" void kernel_launch(void* const* d_in, const int* in_sizes, int n_in,
                              void* d_out, int out_size, void* d_ws, size_t ws_size,
                              hipStream_t stream)
{
  const float* z    = (const float*)d_in[0];
  const float* keys = (const float*)d_in[1];
  const float* ls   = (const float*)d_in[2];
  float* out_sim = (float*)d_out;
  float* out_we  = out_sim + (size_t)B_N * E_N;
  char* ws = (char*)d_ws;
  float*  sinv = (float*)(ws);
  float*  ak   = (float*)(ws + 4096);
  __bf16* sk   = (__bf16*)(ws + 4352);
  __bf16* kT   = (__bf16*)(ws + 135424);
  prep_kernel<<<80, 256, 0, stream>>>(keys, ls, sinv, ak, sk, kT);
  main_kernel<<<B_N / ROWS, 1024, 0, stream>>>(z, sinv, ak, sk, kT, out_sim, out_we);
}